// Round 3
// baseline (383.369 us; speedup 1.0000x reference)
//
#include <hip/hip_runtime.h>
#include <math.h>

// LIF forward: x[B,T,N], thresh[N], tau_x[N] -> spikes[B,T,N], mems[B,T,N]
// Recurrence per (b,n): mem=(x-mem)*sig+mem; spike=mem>=th; mem=spike?0:mem.
// Memory-bound: 384 MiB traffic -> ~64us floor at 6.3 TB/s.
// Numerics: harness ref is f32 numpy (absmax R1 = exactly 1 bf16 ulp);
// replicate f32 op order (sub,mul,add — contract OFF) so we track it bitwise;
// sigmoid via f64 exp rounded to f32 (~correctly-rounded f32 sigmoid).
// R3 fix: __builtin_nontemporal_store needs a clang ext_vector_type, not
// HIP's float4 class -> use native v4f throughout.

constexpr int B = 32;
constexpr int T = 64;
constexpr int N = 16384;
constexpr int N4 = N / 4;

typedef float v4f __attribute__((ext_vector_type(4)));

__global__ __launch_bounds__(256) void lif_fwd_kernel(
    const v4f* __restrict__ x,       // [B, T, N4]
    const v4f* __restrict__ thresh,  // [N4]
    const v4f* __restrict__ tau_x,   // [N4]
    v4f* __restrict__ spikes,        // [B, T, N4]
    v4f* __restrict__ mems)          // [B, T, N4]
{
#pragma clang fp contract(off)
    const int g = blockIdx.x * blockDim.x + threadIdx.x;
    const int n4 = g & (N4 - 1);   // N4 = 4096
    const int b  = g >> 12;

    const v4f th = thresh[n4];
    const v4f tx = tau_x[n4];

    // f32-correctly-rounded sigmoid via f64 exp
    const float sig0 = (float)(1.0 / (1.0 + exp(-(double)tx.x)));
    const float sig1 = (float)(1.0 / (1.0 + exp(-(double)tx.y)));
    const float sig2 = (float)(1.0 / (1.0 + exp(-(double)tx.z)));
    const float sig3 = (float)(1.0 / (1.0 + exp(-(double)tx.w)));

    float m0 = 0.0f, m1 = 0.0f, m2 = 0.0f, m3 = 0.0f;

    const size_t base = (size_t)b * T * N4 + n4;
    const v4f* __restrict__ xp = x + base;
    v4f* __restrict__ sp = spikes + base;
    v4f* __restrict__ mp = mems + base;

#pragma unroll 8
    for (int t = 0; t < T; ++t) {
        const int off = t * N4;
        const v4f xv = xp[off];   // independent of m -> hoisted, 8 in flight

        // exact np f32 op order: sub, mul, add (contract off = no FMA)
        m0 = (xv.x - m0) * sig0 + m0;
        m1 = (xv.y - m1) * sig1 + m1;
        m2 = (xv.z - m2) * sig2 + m2;
        m3 = (xv.w - m3) * sig3 + m3;

        const float s0 = (m0 >= th.x) ? 1.0f : 0.0f;
        const float s1 = (m1 >= th.y) ? 1.0f : 0.0f;
        const float s2 = (m2 >= th.z) ? 1.0f : 0.0f;
        const float s3 = (m3 >= th.w) ? 1.0f : 0.0f;

        m0 = (s0 != 0.0f) ? 0.0f : m0;
        m1 = (s1 != 0.0f) ? 0.0f : m1;
        m2 = (s2 != 0.0f) ? 0.0f : m2;
        m3 = (s3 != 0.0f) ? 0.0f : m3;

        // outputs are write-once streams: nontemporal keeps L2/L3 clean for x
        v4f sv; sv.x = s0; sv.y = s1; sv.z = s2; sv.w = s3;
        v4f mv; mv.x = m0; mv.y = m1; mv.z = m2; mv.w = m3;
        __builtin_nontemporal_store(sv, sp + off);
        __builtin_nontemporal_store(mv, mp + off);
    }
}

extern "C" void kernel_launch(void* const* d_in, const int* in_sizes, int n_in,
                              void* d_out, int out_size, void* d_ws, size_t ws_size,
                              hipStream_t stream) {
    const v4f* x      = (const v4f*)d_in[0];
    const v4f* thresh = (const v4f*)d_in[1];
    const v4f* tau_x  = (const v4f*)d_in[2];

    float* out = (float*)d_out;
    v4f* spikes = (v4f*)out;                       // first B*T*N floats
    v4f* mems   = (v4f*)(out + (size_t)B * T * N); // second B*T*N floats

    const int total_threads = B * N4;  // 131072
    const int block = 256;
    const int grid = total_threads / block;  // 512

    lif_fwd_kernel<<<grid, block, 0, stream>>>(x, thresh, tau_x, spikes, mems);
}

// Round 4
// 364.416 us; speedup vs baseline: 1.0520x; 1.0520x over previous
//
#include <hip/hip_runtime.h>
#include <math.h>

// LIF forward: x[B,T,N], thresh[N], tau_x[N] -> spikes[B,T,N], mems[B,T,N]
// Recurrence per (b,n): mem=(x-mem)*sig+mem; spike=mem>=th; mem=spike?0:mem.
// Memory-bound: 402 MB traffic -> ~65us floor at 6.3 TB/s.
// Numerics: f32 op order (contract off) matches np ref to 1 bf16 ulp —
// comparison floor (absmax identical for f64 and f32 recurrence).
// R4: float2/thread -> 4096 waves (4/SIMD, was 2/SIMD) to raise memory-level
// parallelism; in-flight bytes/CU 8 KiB -> 64 KiB vs ~9 KiB BW*latency need.
// Plain stores (nontemporal was neutral-to-negative in R3).

constexpr int B = 32;
constexpr int T = 64;
constexpr int N = 16384;
constexpr int N2 = N / 2;  // 8192

typedef float v2f __attribute__((ext_vector_type(2)));

__global__ __launch_bounds__(256) void lif_fwd_kernel(
    const v2f* __restrict__ x,       // [B, T, N2]
    const v2f* __restrict__ thresh,  // [N2]
    const v2f* __restrict__ tau_x,   // [N2]
    v2f* __restrict__ spikes,        // [B, T, N2]
    v2f* __restrict__ mems)          // [B, T, N2]
{
#pragma clang fp contract(off)
    const int g = blockIdx.x * blockDim.x + threadIdx.x;
    const int n2 = g & (N2 - 1);   // N2 = 8192
    const int b  = g >> 13;

    const v2f th = thresh[n2];
    const v2f tx = tau_x[n2];

    // f32-correctly-rounded sigmoid via f64 exp
    const float sig0 = (float)(1.0 / (1.0 + exp(-(double)tx.x)));
    const float sig1 = (float)(1.0 / (1.0 + exp(-(double)tx.y)));

    float m0 = 0.0f, m1 = 0.0f;

    const size_t base = (size_t)b * T * N2 + n2;
    const v2f* __restrict__ xp = x + base;
    v2f* __restrict__ sp = spikes + base;
    v2f* __restrict__ mp = mems + base;

#pragma unroll 8
    for (int t = 0; t < T; ++t) {
        const int off = t * N2;
        const v2f xv = xp[off];   // independent of m -> hoisted by unroll

        // exact np f32 op order: sub, mul, add (contract off = no FMA)
        m0 = (xv.x - m0) * sig0 + m0;
        m1 = (xv.y - m1) * sig1 + m1;

        const float s0 = (m0 >= th.x) ? 1.0f : 0.0f;
        const float s1 = (m1 >= th.y) ? 1.0f : 0.0f;

        m0 = (s0 != 0.0f) ? 0.0f : m0;
        m1 = (s1 != 0.0f) ? 0.0f : m1;

        v2f sv; sv.x = s0; sv.y = s1;
        v2f mv; mv.x = m0; mv.y = m1;
        sp[off] = sv;
        mp[off] = mv;
    }
}

extern "C" void kernel_launch(void* const* d_in, const int* in_sizes, int n_in,
                              void* d_out, int out_size, void* d_ws, size_t ws_size,
                              hipStream_t stream) {
    const v2f* x      = (const v2f*)d_in[0];
    const v2f* thresh = (const v2f*)d_in[1];
    const v2f* tau_x  = (const v2f*)d_in[2];

    float* out = (float*)d_out;
    v2f* spikes = (v2f*)out;                       // first B*T*N floats
    v2f* mems   = (v2f*)(out + (size_t)B * T * N); // second B*T*N floats

    const int total_threads = B * N2;  // 262144
    const int block = 256;
    const int grid = total_threads / block;  // 1024

    lif_fwd_kernel<<<grid, block, 0, stream>>>(x, thresh, tau_x, spikes, mems);
}